// Round 1
// baseline (773.876 us; speedup 1.0000x reference)
//
#include <hip/hip_runtime.h>

#define N_NODES 100000
#define N_EDGES 1600000

// ---------------------------------------------------------------------------
// Fused linear kernel: Y[row][col] = dot(X[row], W[col]) (+bias) (+agg/cnt) (relu)
// IN fixed at 64. OUT in {64, 32}. ROWS = 256/OUT rows per 256-thread block.
// W is [OUT][64] row-major (torch Linear weight layout); staged transposed in
// LDS with +1 pad so the compute read is 2-way-bank at worst (free on CDNA4).
// ---------------------------------------------------------------------------
template <int OUT, int ROWS, bool HAS_BIAS, bool RELU, bool FUSE_AGG>
__global__ __launch_bounds__(256) void linear_kernel(
    const float* __restrict__ X, const float* __restrict__ W,
    const float* __restrict__ bias, const float* __restrict__ agg,
    const float* __restrict__ cnt, float* __restrict__ Y, int nrows) {
  __shared__ float sW[64 * (OUT + 1)];
  __shared__ float sX[ROWS * 64];
  const int t = threadIdx.x;
  const int base = blockIdx.x * ROWS;

  // Stage W transposed: sW[k][col] = W[col][k]
  for (int idx = t; idx < OUT * 64; idx += 256) {
    const int col = idx >> 6, k = idx & 63;
    sW[k * (OUT + 1) + col] = W[idx];
  }
  // Stage ROWS rows of X
  for (int idx = t; idx < ROWS * 64; idx += 256) {
    const int r = idx >> 6, k = idx & 63;
    const int row = base + r;
    sX[idx] = (row < nrows) ? X[(size_t)row * 64 + k] : 0.0f;
  }
  __syncthreads();

  const int ty = t / OUT, tx = t % OUT;
  const int row = base + ty;
  if (row >= nrows) return;

  float acc = HAS_BIAS ? bias[tx] : 0.0f;
#pragma unroll
  for (int k = 0; k < 64; ++k)
    acc = fmaf(sX[ty * 64 + k], sW[k * (OUT + 1) + tx], acc);

  if (FUSE_AGG) {
    const float c = fmaxf(cnt[row], 1.0f);
    acc += agg[(size_t)row * OUT + tx] * (1.0f / c);
  }
  if (RELU) acc = fmaxf(acc, 0.0f);
  Y[(size_t)row * OUT + tx] = acc;
}

// ---------------------------------------------------------------------------
// Edge scatter: F lanes per edge; coalesced row gather from H[src], atomic
// accumulate into agg[dst].
// ---------------------------------------------------------------------------
template <int F>
__global__ __launch_bounds__(256) void scatter_kernel(
    const float* __restrict__ H, const int* __restrict__ ei,
    float* __restrict__ agg) {
  const long long t = (long long)blockIdx.x * 256 + threadIdx.x;
  const int e = (int)(t / F);
  const int f = (int)(t % F);
  if (e >= N_EDGES) return;
  const int s = ei[e];
  const int d = ei[N_EDGES + e];
  atomicAdd(&agg[(size_t)d * F + f], H[(size_t)s * F + f]);
}

// Degree count (same dst list both layers -> computed once)
__global__ __launch_bounds__(256) void count_kernel(const int* __restrict__ ei,
                                                    float* __restrict__ cnt) {
  const int e = blockIdx.x * 256 + threadIdx.x;
  if (e >= N_EDGES) return;
  atomicAdd(&cnt[ei[N_EDGES + e]], 1.0f);
}

extern "C" void kernel_launch(void* const* d_in, const int* in_sizes, int n_in,
                              void* d_out, int out_size, void* d_ws,
                              size_t ws_size, hipStream_t stream) {
  const float* x = (const float*)d_in[0];
  const int* ei = (const int*)d_in[1];
  const float* Wl0 = (const float*)d_in[2];
  const float* bl0 = (const float*)d_in[3];
  const float* Wr0 = (const float*)d_in[4];
  const float* Wl1 = (const float*)d_in[5];
  const float* bl1 = (const float*)d_in[6];
  const float* Wr1 = (const float*)d_in[7];
  float* out = (float*)d_out;

  const int N = N_NODES;

  // Workspace layout (floats):
  //   h0/h : N*64   (h0 = lin_l0 out; later reused for h = layer-0 output)
  //   agg0 : N*64
  //   cnt  : N
  //   h1   : N*32
  float* ws = (float*)d_ws;
  float* h0 = ws;
  float* agg0 = h0 + (size_t)N * 64;
  float* cnt = agg0 + (size_t)N * 64;
  float* h1 = cnt + N;

  hipMemsetAsync(agg0, 0, (size_t)N * 64 * sizeof(float), stream);
  hipMemsetAsync(cnt, 0, (size_t)N * sizeof(float), stream);
  hipMemsetAsync(d_out, 0, (size_t)N * 32 * sizeof(float), stream);

  const dim3 blk(256);

  // ---- Layer 0 ----
  // h0 = x @ Wl0.T + bl0
  linear_kernel<64, 4, true, false, false>
      <<<(N + 3) / 4, blk, 0, stream>>>(x, Wl0, bl0, nullptr, nullptr, h0, N);
  // degree
  count_kernel<<<(N_EDGES + 255) / 256, blk, 0, stream>>>(ei, cnt);
  // agg0[dst] += h0[src]
  scatter_kernel<64>
      <<<(int)(((long long)N_EDGES * 64 + 255) / 256), blk, 0, stream>>>(
          h0, ei, agg0);
  // h = relu(agg0/max(cnt,1) + x @ Wr0.T)   (written over h0)
  linear_kernel<64, 4, false, true, true>
      <<<(N + 3) / 4, blk, 0, stream>>>(x, Wr0, nullptr, agg0, cnt, h0, N);

  // ---- Layer 1 ----
  // h1 = h @ Wl1.T + bl1
  linear_kernel<32, 8, true, false, false>
      <<<(N + 7) / 8, blk, 0, stream>>>(h0, Wl1, bl1, nullptr, nullptr, h1, N);
  // out(agg1)[dst] += h1[src]   (d_out doubles as accumulator, memset above)
  scatter_kernel<32>
      <<<(int)(((long long)N_EDGES * 32 + 255) / 256), blk, 0, stream>>>(
          h1, ei, out);
  // out = agg1/max(cnt,1) + h @ Wr1.T   (in-place combine on d_out)
  linear_kernel<32, 8, false, false, true>
      <<<(N + 7) / 8, blk, 0, stream>>>(h0, Wr1, nullptr, out, cnt, out, N);
}

// Round 2
// 526.834 us; speedup vs baseline: 1.4689x; 1.4689x over previous
//
#include <hip/hip_runtime.h>

#define N_NODES 100000
#define N_EDGES 1600000
#define NB_SCAN ((N_NODES + 255) / 256)  // 391 blocks of 256

// ---------------------------------------------------------------------------
// Fused linear kernel: Y[row][col] = dot(X[row], W[col]) (+bias) (+agg) (relu)
// IN fixed at 64. OUT in {64, 32}. ROWS = 256/OUT rows per 256-thread block.
// agg (if FUSE_AGG) is already the mean — just added.
// ---------------------------------------------------------------------------
template <int OUT, int ROWS, bool HAS_BIAS, bool RELU, bool FUSE_AGG>
__global__ __launch_bounds__(256) void linear_kernel(
    const float* __restrict__ X, const float* __restrict__ W,
    const float* __restrict__ bias, const float* __restrict__ agg,
    float* __restrict__ Y, int nrows) {
  __shared__ float sW[64 * (OUT + 1)];
  __shared__ float sX[ROWS * 64];
  const int t = threadIdx.x;
  const int base = blockIdx.x * ROWS;

  // Stage W transposed: sW[k][col] = W[col][k]
  for (int idx = t; idx < OUT * 64; idx += 256) {
    const int col = idx >> 6, k = idx & 63;
    sW[k * (OUT + 1) + col] = W[idx];
  }
  // Stage ROWS rows of X
  for (int idx = t; idx < ROWS * 64; idx += 256) {
    const int r = idx >> 6, k = idx & 63;
    const int row = base + r;
    sX[idx] = (row < nrows) ? X[(size_t)row * 64 + k] : 0.0f;
  }
  __syncthreads();

  const int ty = t / OUT, tx = t % OUT;
  const int row = base + ty;
  if (row >= nrows) return;

  float acc = HAS_BIAS ? bias[tx] : 0.0f;
#pragma unroll
  for (int k = 0; k < 64; ++k)
    acc = fmaf(sX[ty * 64 + k], sW[k * (OUT + 1) + tx], acc);

  if (FUSE_AGG) acc += agg[(size_t)row * OUT + tx];
  if (RELU) acc = fmaxf(acc, 0.0f);
  Y[(size_t)row * OUT + tx] = acc;
}

// ---------------------------------------------------------------------------
// CSR build: degree count -> 3-kernel exclusive scan -> bucket fill.
// Only u32 atomics (cheap fire-and-forget), no float atomics anywhere.
// ---------------------------------------------------------------------------
__global__ __launch_bounds__(256) void count_kernel(const int* __restrict__ ei,
                                                    unsigned* __restrict__ deg) {
  const int e = blockIdx.x * 256 + threadIdx.x;
  if (e >= N_EDGES) return;
  atomicAdd(&deg[ei[N_EDGES + e]], 1u);
}

__global__ __launch_bounds__(256) void scan_block(
    const unsigned* __restrict__ deg, unsigned* __restrict__ rowptr,
    unsigned* __restrict__ bsum) {
  __shared__ unsigned s[256];
  const int t = threadIdx.x;
  const int i = blockIdx.x * 256 + t;
  const unsigned v = (i < N_NODES) ? deg[i] : 0u;
  s[t] = v;
  __syncthreads();
  for (int off = 1; off < 256; off <<= 1) {
    const unsigned u = (t >= off) ? s[t - off] : 0u;
    __syncthreads();
    s[t] += u;
    __syncthreads();
  }
  if (i < N_NODES) rowptr[i] = s[t] - v;  // exclusive within block
  if (t == 255) bsum[blockIdx.x] = s[255];
}

__global__ __launch_bounds__(512) void scan_sums(
    const unsigned* __restrict__ bsum, unsigned* __restrict__ boff) {
  __shared__ unsigned s[512];
  const int t = threadIdx.x;
  const unsigned v = (t < NB_SCAN) ? bsum[t] : 0u;
  s[t] = v;
  __syncthreads();
  for (int off = 1; off < 512; off <<= 1) {
    const unsigned u = (t >= off) ? s[t - off] : 0u;
    __syncthreads();
    s[t] += u;
    __syncthreads();
  }
  if (t < NB_SCAN) boff[t] = s[t] - v;
}

__global__ __launch_bounds__(256) void scan_add(
    unsigned* __restrict__ rowptr, const unsigned* __restrict__ boff,
    unsigned* __restrict__ cursor) {
  const int i = blockIdx.x * 256 + threadIdx.x;
  if (i == 0) rowptr[N_NODES] = N_EDGES;
  if (i < N_NODES) {
    const unsigned r = rowptr[i] + boff[blockIdx.x];
    rowptr[i] = r;
    cursor[i] = r;
  }
}

__global__ __launch_bounds__(256) void fill_kernel(
    const int* __restrict__ ei, unsigned* __restrict__ cursor,
    unsigned* __restrict__ csr_src) {
  const int e = blockIdx.x * 256 + threadIdx.x;
  if (e >= N_EDGES) return;
  const int s = ei[e];
  const int d = ei[N_EDGES + e];
  const unsigned pos = atomicAdd(&cursor[d], 1u);
  csr_src[pos] = (unsigned)s;
}

// ---------------------------------------------------------------------------
// Gather-aggregate (mean): one 64-lane wave per destination node.
// F=64: lane = feature; 2-wide unrolled edge loop for ILP.
// F=32: lanes 0-31 / 32-63 process alternating edges, combined via shfl_xor.
// Writes agg = sum/deg (0 for isolated nodes) — fully overwrites output.
// ---------------------------------------------------------------------------
template <int F>
__global__ __launch_bounds__(256) void gather_agg(
    const float* __restrict__ H, const unsigned* __restrict__ rowptr,
    const unsigned* __restrict__ csr_src, float* __restrict__ agg) {
  const int node = (int)((blockIdx.x * 256 + threadIdx.x) >> 6);
  const int lane = threadIdx.x & 63;
  if (node >= N_NODES) return;
  const unsigned beg = rowptr[node], end = rowptr[node + 1];
  const float inv = (end > beg) ? 1.0f / (float)(end - beg) : 0.0f;
  if (F == 64) {
    float a0 = 0.0f, a1 = 0.0f;
    unsigned e = beg;
    for (; e + 1 < end; e += 2) {
      const unsigned s0 = csr_src[e], s1 = csr_src[e + 1];
      a0 += H[(size_t)s0 * 64 + lane];
      a1 += H[(size_t)s1 * 64 + lane];
    }
    if (e < end) a0 += H[(size_t)csr_src[e] * 64 + lane];
    agg[(size_t)node * 64 + lane] = (a0 + a1) * inv;
  } else {
    const int f = lane & 31, sub = lane >> 5;
    float a = 0.0f;
    for (unsigned e = beg + sub; e < end; e += 2)
      a += H[(size_t)csr_src[e] * 32 + f];
    a += __shfl_xor(a, 32, 64);
    if (lane < 32) agg[(size_t)node * 32 + f] = a * inv;
  }
}

extern "C" void kernel_launch(void* const* d_in, const int* in_sizes, int n_in,
                              void* d_out, int out_size, void* d_ws,
                              size_t ws_size, hipStream_t stream) {
  const float* x = (const float*)d_in[0];
  const int* ei = (const int*)d_in[1];
  const float* Wl0 = (const float*)d_in[2];
  const float* bl0 = (const float*)d_in[3];
  const float* Wr0 = (const float*)d_in[4];
  const float* Wl1 = (const float*)d_in[5];
  const float* bl1 = (const float*)d_in[6];
  const float* Wr1 = (const float*)d_in[7];
  float* out = (float*)d_out;

  const int N = N_NODES;

  // Workspace layout:
  //   bufA : N*64 f32  (h0 = lin_l0 out; later reused for h1 [N,32])
  //   bufB : N*64 f32  (agg0; then overwritten in-place by h = layer-0 output)
  //   deg, rowptr[N+1], cursor, bsum[512], boff[512], csr_src[E] : u32
  float* bufA = (float*)d_ws;
  float* bufB = bufA + (size_t)N * 64;
  unsigned* deg = (unsigned*)(bufB + (size_t)N * 64);
  unsigned* rowptr = deg + N;
  unsigned* cursor = rowptr + (N + 1);
  unsigned* bsum = cursor + N;
  unsigned* boff = bsum + 512;
  unsigned* csr_src = boff + 512;

  hipMemsetAsync(deg, 0, (size_t)N * sizeof(unsigned), stream);

  const dim3 blk(256);
  const int EB = (N_EDGES + 255) / 256;

  // ---- CSR build (graph identical for both layers) ----
  count_kernel<<<EB, blk, 0, stream>>>(ei, deg);
  scan_block<<<NB_SCAN, blk, 0, stream>>>(deg, rowptr, bsum);
  scan_sums<<<1, 512, 0, stream>>>(bsum, boff);
  scan_add<<<NB_SCAN, blk, 0, stream>>>(rowptr, boff, cursor);
  fill_kernel<<<EB, blk, 0, stream>>>(ei, cursor, csr_src);

  // ---- Layer 0 ----
  // h0 = x @ Wl0.T + bl0
  linear_kernel<64, 4, true, false, false>
      <<<(N + 3) / 4, blk, 0, stream>>>(x, Wl0, bl0, nullptr, bufA, N);
  // agg0 = scatter-mean(h0[src] -> dst)  (pure gather via CSR)
  gather_agg<64><<<(N * 64 + 255) / 256, blk, 0, stream>>>(bufA, rowptr,
                                                           csr_src, bufB);
  // h = relu(agg0 + x @ Wr0.T)  — in-place over bufB
  linear_kernel<64, 4, false, true, true>
      <<<(N + 3) / 4, blk, 0, stream>>>(x, Wr0, nullptr, bufB, bufB, N);

  // ---- Layer 1 ----
  // h1 = h @ Wl1.T + bl1  (into bufA, which is free now)
  linear_kernel<32, 8, true, false, false>
      <<<(N + 7) / 8, blk, 0, stream>>>(bufB, Wl1, bl1, nullptr, bufA, N);
  // agg1 = scatter-mean(h1[src] -> dst) straight into d_out (full overwrite)
  gather_agg<32><<<(N * 64 + 255) / 256, blk, 0, stream>>>(bufA, rowptr,
                                                           csr_src, out);
  // out = agg1 + h @ Wr1.T  — in-place over d_out
  linear_kernel<32, 8, false, false, true>
      <<<(N + 7) / 8, blk, 0, stream>>>(bufB, Wr1, nullptr, out, out, N);
}

// Round 3
// 483.081 us; speedup vs baseline: 1.6020x; 1.0906x over previous
//
#include <hip/hip_runtime.h>

#define N_NODES 100000
#define N_EDGES 1600000
#define NB_SCAN ((N_NODES + 255) / 256)  // 391 blocks of 256
#define EBLK ((N_EDGES + 2047) / 2048)   // 782 blocks of 2048 edges

// ---------------------------------------------------------------------------
// Fused layer-0 linear: h0 = x@Wl0.T + bl0  AND  r0 = x@Wr0.T, one pass over x.
// 8 rows/block; sW[k][c]: c<64 -> Wl, c>=64 -> Wr (stride 129: 2-way bank max).
// ---------------------------------------------------------------------------
__global__ __launch_bounds__(256) void linear_fused0(
    const float* __restrict__ X, const float* __restrict__ Wl,
    const float* __restrict__ bl, const float* __restrict__ Wr,
    float* __restrict__ H0, float* __restrict__ R0) {
  __shared__ float sW[64 * 129];
  __shared__ float sX[8 * 64];
  const int t = threadIdx.x;
  const int base = blockIdx.x * 8;  // 100000 % 8 == 0
  for (int idx = t; idx < 64 * 64; idx += 256) {
    const int c = idx >> 6, k = idx & 63;
    sW[k * 129 + c] = Wl[idx];
    sW[k * 129 + 64 + c] = Wr[idx];
  }
  for (int idx = t; idx < 8 * 64; idx += 256)
    sX[idx] = X[(size_t)base * 64 + idx];
  __syncthreads();

  const int c = t & 127, r0 = t >> 7;  // r0: 0..1
  const bool left = c < 64;
  const float bias = left ? bl[c] : 0.0f;
  float acc[4] = {bias, bias, bias, bias};
  for (int k = 0; k < 64; ++k) {
    const float w = sW[k * 129 + c];
#pragma unroll
    for (int i = 0; i < 4; ++i)
      acc[i] = fmaf(sX[(r0 + 2 * i) * 64 + k], w, acc[i]);
  }
#pragma unroll
  for (int i = 0; i < 4; ++i) {
    const size_t row = base + r0 + 2 * i;
    if (left) H0[row * 64 + c] = acc[i];
    else      R0[row * 64 + (c - 64)] = acc[i];
  }
}

// ---------------------------------------------------------------------------
// Fused layer-1 linear: h1 = h@Wl1.T + bl1  AND  hr1 = h@Wr1.T. 16 rows/block.
// ---------------------------------------------------------------------------
__global__ __launch_bounds__(256) void linear_dual1(
    const float* __restrict__ H, const float* __restrict__ Wl,
    const float* __restrict__ bl, const float* __restrict__ Wr,
    float* __restrict__ H1, float* __restrict__ HR1) {
  __shared__ float sW[64 * 65];
  __shared__ float sX[16 * 64];
  const int t = threadIdx.x;
  const int base = blockIdx.x * 16;  // 100000 % 16 == 0
  for (int idx = t; idx < 32 * 64; idx += 256) {
    const int c = idx >> 6, k = idx & 63;
    sW[k * 65 + c] = Wl[idx];
    sW[k * 65 + 32 + c] = Wr[idx];
  }
  for (int idx = t; idx < 16 * 64; idx += 256)
    sX[idx] = H[(size_t)base * 64 + idx];
  __syncthreads();

  const int c = t & 63, r0 = t >> 6;  // r0: 0..3
  const bool left = c < 32;
  const float bias = left ? bl[c] : 0.0f;
  float acc[4] = {bias, bias, bias, bias};
  for (int k = 0; k < 64; ++k) {
    const float w = sW[k * 65 + c];
#pragma unroll
    for (int i = 0; i < 4; ++i)
      acc[i] = fmaf(sX[(r0 + 4 * i) * 64 + k], w, acc[i]);
  }
#pragma unroll
  for (int i = 0; i < 4; ++i) {
    const size_t row = base + r0 + 4 * i;
    if (left) H1[row * 32 + c] = acc[i];
    else      HR1[row * 32 + (c - 32)] = acc[i];
  }
}

// ---------------------------------------------------------------------------
// CSR build, locality-ranged: blockIdx.y = pass; each pass touches only a
// dst sub-range so cursor/csr writes stay in a ~400KB L2-resident window.
// Pass blocks dispatch in y order -> approximate temporal locality.
// ---------------------------------------------------------------------------
__global__ __launch_bounds__(256) void count_ranged(const int* __restrict__ ei,
                                                    unsigned* __restrict__ deg) {
  const int lo = blockIdx.y * (N_NODES / 8), hi = lo + (N_NODES / 8);
  const int base = blockIdx.x * 2048;
#pragma unroll
  for (int i = 0; i < 8; ++i) {
    const int e = base + i * 256 + threadIdx.x;
    if (e < N_EDGES) {
      const int d = ei[N_EDGES + e];
      if (d >= lo && d < hi) atomicAdd(&deg[d], 1u);
    }
  }
}

__global__ __launch_bounds__(256) void scan_block(
    const unsigned* __restrict__ deg, unsigned* __restrict__ rowptr,
    unsigned* __restrict__ bsum) {
  __shared__ unsigned s[256];
  const int t = threadIdx.x;
  const int i = blockIdx.x * 256 + t;
  const unsigned v = (i < N_NODES) ? deg[i] : 0u;
  s[t] = v;
  __syncthreads();
  for (int off = 1; off < 256; off <<= 1) {
    const unsigned u = (t >= off) ? s[t - off] : 0u;
    __syncthreads();
    s[t] += u;
    __syncthreads();
  }
  if (i < N_NODES) rowptr[i] = s[t] - v;
  if (t == 255) bsum[blockIdx.x] = s[255];
}

__global__ __launch_bounds__(512) void scan_sums(
    const unsigned* __restrict__ bsum, unsigned* __restrict__ boff) {
  __shared__ unsigned s[512];
  const int t = threadIdx.x;
  const unsigned v = (t < NB_SCAN) ? bsum[t] : 0u;
  s[t] = v;
  __syncthreads();
  for (int off = 1; off < 512; off <<= 1) {
    const unsigned u = (t >= off) ? s[t - off] : 0u;
    __syncthreads();
    s[t] += u;
    __syncthreads();
  }
  if (t < NB_SCAN) boff[t] = s[t] - v;
}

__global__ __launch_bounds__(256) void scan_add(
    unsigned* __restrict__ rowptr, const unsigned* __restrict__ boff,
    unsigned* __restrict__ cursor) {
  const int i = blockIdx.x * 256 + threadIdx.x;
  if (i == 0) rowptr[N_NODES] = N_EDGES;
  if (i < N_NODES) {
    const unsigned r = rowptr[i] + boff[blockIdx.x];
    rowptr[i] = r;
    cursor[i] = r;
  }
}

__global__ __launch_bounds__(256) void fill_ranged(
    const int* __restrict__ ei, unsigned* __restrict__ cursor,
    unsigned* __restrict__ csr_src) {
  const int lo = blockIdx.y * (N_NODES / 16), hi = lo + (N_NODES / 16);
  const int base = blockIdx.x * 2048;
#pragma unroll
  for (int i = 0; i < 8; ++i) {
    const int e = base + i * 256 + threadIdx.x;
    if (e < N_EDGES) {
      const int d = ei[N_EDGES + e];
      if (d >= lo && d < hi) {
        const unsigned pos = atomicAdd(&cursor[d], 1u);
        csr_src[pos] = (unsigned)ei[e];
      }
    }
  }
}

// ---------------------------------------------------------------------------
// Gather-aggregate + combine: one wave per dst node, float4 per lane.
// G = F/4 lanes per source row; NG = 64/G rows in flight; 2-deep unroll.
// out[node] = mean(H[src]) + base_row[node], optional relu. Full overwrite.
// ---------------------------------------------------------------------------
template <int F, bool RELU>
__global__ __launch_bounds__(256) void gather_comb(
    const float* __restrict__ H, const unsigned* __restrict__ rowptr,
    const unsigned* __restrict__ csr_src, const float* __restrict__ base_row,
    float* __restrict__ outp) {
  constexpr int G = F / 4;
  constexpr int NG = 64 / G;
  const int node = (int)((blockIdx.x * 256 + threadIdx.x) >> 6);
  const int lane = threadIdx.x & 63;
  if (node >= N_NODES) return;
  const int g = lane / G, q = lane % G;
  const unsigned beg = rowptr[node], end = rowptr[node + 1];
  const float inv = (end > beg) ? 1.0f / (float)(end - beg) : 0.0f;
  const float4* __restrict__ H4 = (const float4*)H;

  float4 a0 = {0.f, 0.f, 0.f, 0.f}, a1 = {0.f, 0.f, 0.f, 0.f};
  unsigned e = beg + g;
  for (; e + NG < end; e += 2 * NG) {
    const unsigned s0 = csr_src[e], s1 = csr_src[e + NG];
    const float4 v0 = H4[(size_t)s0 * G + q];
    const float4 v1 = H4[(size_t)s1 * G + q];
    a0.x += v0.x; a0.y += v0.y; a0.z += v0.z; a0.w += v0.w;
    a1.x += v1.x; a1.y += v1.y; a1.z += v1.z; a1.w += v1.w;
  }
  if (e < end) {
    const float4 v = H4[(size_t)csr_src[e] * G + q];
    a0.x += v.x; a0.y += v.y; a0.z += v.z; a0.w += v.w;
  }
  float sx = a0.x + a1.x, sy = a0.y + a1.y;
  float sz = a0.z + a1.z, sw = a0.w + a1.w;
#pragma unroll
  for (int m = G; m < 64; m <<= 1) {
    sx += __shfl_xor(sx, m, 64);
    sy += __shfl_xor(sy, m, 64);
    sz += __shfl_xor(sz, m, 64);
    sw += __shfl_xor(sw, m, 64);
  }
  if (g == 0) {
    const float4 b = ((const float4*)base_row)[(size_t)node * G + q];
    float4 r;
    r.x = sx * inv + b.x;
    r.y = sy * inv + b.y;
    r.z = sz * inv + b.z;
    r.w = sw * inv + b.w;
    if (RELU) {
      r.x = fmaxf(r.x, 0.f); r.y = fmaxf(r.y, 0.f);
      r.z = fmaxf(r.z, 0.f); r.w = fmaxf(r.w, 0.f);
    }
    ((float4*)outp)[(size_t)node * G + q] = r;
  }
}

extern "C" void kernel_launch(void* const* d_in, const int* in_sizes, int n_in,
                              void* d_out, int out_size, void* d_ws,
                              size_t ws_size, hipStream_t stream) {
  const float* x = (const float*)d_in[0];
  const int* ei = (const int*)d_in[1];
  const float* Wl0 = (const float*)d_in[2];
  const float* bl0 = (const float*)d_in[3];
  const float* Wr0 = (const float*)d_in[4];
  const float* Wl1 = (const float*)d_in[5];
  const float* bl1 = (const float*)d_in[6];
  const float* Wr1 = (const float*)d_in[7];
  float* out = (float*)d_out;

  const int N = N_NODES;

  // Workspace:
  //   bufA : N*64 f32  h0; later h1 = bufA[0,N*32), hr1 = bufA[N*32,N*64)
  //   bufB : N*64 f32  r0 -> h (in-place per-row during gather64)
  //   deg, rowptr[N+1], cursor, bsum[512], boff[512], csr_src[E] : u32
  float* bufA = (float*)d_ws;
  float* bufB = bufA + (size_t)N * 64;
  unsigned* deg = (unsigned*)(bufB + (size_t)N * 64);
  unsigned* rowptr = deg + N;
  unsigned* cursor = rowptr + (N + 1);
  unsigned* bsum = cursor + N;
  unsigned* boff = bsum + 512;
  unsigned* csr_src = boff + 512;
  float* h1 = bufA;
  float* hr1 = bufA + (size_t)N * 32;

  hipMemsetAsync(deg, 0, (size_t)N * sizeof(unsigned), stream);

  const dim3 blk(256);

  // ---- CSR build (graph identical for both layers), locality-ranged ----
  count_ranged<<<dim3(EBLK, 8), blk, 0, stream>>>(ei, deg);
  scan_block<<<NB_SCAN, blk, 0, stream>>>(deg, rowptr, bsum);
  scan_sums<<<1, 512, 0, stream>>>(bsum, boff);
  scan_add<<<NB_SCAN, blk, 0, stream>>>(rowptr, boff, cursor);
  fill_ranged<<<dim3(EBLK, 16), blk, 0, stream>>>(ei, cursor, csr_src);

  // ---- Layer 0: h0 = x@Wl0.T+bl0, r0 = x@Wr0.T (one pass over x) ----
  linear_fused0<<<N / 8, blk, 0, stream>>>(x, Wl0, bl0, Wr0, bufA, bufB);
  // h = relu(mean(h0[src]) + r0)  — written in-place over r0 (per-row safe)
  gather_comb<64, true><<<(N * 64 + 255) / 256, blk, 0, stream>>>(
      bufA, rowptr, csr_src, bufB, bufB);

  // ---- Layer 1: h1 = h@Wl1.T+bl1, hr1 = h@Wr1.T (one pass over h) ----
  linear_dual1<<<N / 16, blk, 0, stream>>>(bufB, Wl1, bl1, Wr1, h1, hr1);
  // out = mean(h1[src]) + hr1  — full overwrite of d_out, no memset needed
  gather_comb<32, false><<<(N * 64 + 255) / 256, blk, 0, stream>>>(
      h1, rowptr, csr_src, hr1, out);
}

// Round 4
// 320.814 us; speedup vs baseline: 2.4122x; 1.5058x over previous
//
#include <hip/hip_runtime.h>

#define N_NODES 100000
#define N_EDGES 1600000
#define NB_SCAN ((N_NODES + 255) / 256)  // 391 blocks of 256
#define EBLK ((N_EDGES + 2047) / 2048)   // 782 blocks of 2048 edges
#define NTILES ((N_NODES + 63) / 64)     // 1563 row tiles of 64

__device__ __forceinline__ void fma4(float4& a, float s, const float4& w) {
  a.x = fmaf(s, w.x, a.x);
  a.y = fmaf(s, w.y, a.y);
  a.z = fmaf(s, w.z, a.z);
  a.w = fmaf(s, w.w, a.w);
}

// ---------------------------------------------------------------------------
// GEMM0: h = relu(Wr0 @ x + Wl0 @ aggx + bl0 * (deg>0))   [N,64]
// 64-row tile/block, 256 thr = 16 col-groups x 16 row-groups, 4x4 micro-tile.
// sW k-major [128][68] (k<64 = Wr half vs x; k>=64 = Wl half vs aggx).
// sX [64][68] staged per half (buffer reused; K processed in two 64-chunks).
// ---------------------------------------------------------------------------
__global__ __launch_bounds__(256) void gemm0_kernel(
    const float* __restrict__ X, const float* __restrict__ AGG,
    const float* __restrict__ Wr, const float* __restrict__ Wl,
    const float* __restrict__ bl, const unsigned* __restrict__ deg,
    float* __restrict__ H) {
  __shared__ float sW[128][68];
  __shared__ float sX[64][68];
  const int t = threadIdx.x;
  const int rbase = blockIdx.x * 64;

  // stage weights once: sW[k][c] = Wr[c][k] (k<64), Wl[c][k-64] (k>=64)
  for (int idx = t; idx < 64 * 64; idx += 256) {
    const int c = idx >> 6, k = idx & 63;
    sW[k][c] = Wr[idx];
    sW[k + 64][c] = Wl[idx];
  }

  const int tc = t & 15, tr = t >> 4;
  const int c0 = tc * 4, r0 = tr * 4;
  float4 acc0 = {0, 0, 0, 0}, acc1 = {0, 0, 0, 0};
  float4 acc2 = {0, 0, 0, 0}, acc3 = {0, 0, 0, 0};

  const float* bufs[2] = {X, AGG};
  for (int half = 0; half < 2; ++half) {
    if (half) __syncthreads();
    const float4* __restrict__ B4 = (const float4*)bufs[half];
    for (int f = t; f < 1024; f += 256) {  // 64 rows x 16 float4
      const int row = f >> 4, kq = f & 15;
      const int grow = rbase + row;
      float4 v = {0, 0, 0, 0};
      if (grow < N_NODES) v = B4[(size_t)grow * 16 + kq];
      *(float4*)&sX[row][kq * 4] = v;
    }
    __syncthreads();
    const int kb = half * 64;
#pragma unroll 4
    for (int kc = 0; kc < 64; kc += 4) {
      float4 x0 = *(const float4*)&sX[r0 + 0][kc];
      float4 x1 = *(const float4*)&sX[r0 + 1][kc];
      float4 x2 = *(const float4*)&sX[r0 + 2][kc];
      float4 x3 = *(const float4*)&sX[r0 + 3][kc];
      float4 w0 = *(const float4*)&sW[kb + kc + 0][c0];
      float4 w1 = *(const float4*)&sW[kb + kc + 1][c0];
      float4 w2 = *(const float4*)&sW[kb + kc + 2][c0];
      float4 w3 = *(const float4*)&sW[kb + kc + 3][c0];
      fma4(acc0, x0.x, w0); fma4(acc0, x0.y, w1); fma4(acc0, x0.z, w2); fma4(acc0, x0.w, w3);
      fma4(acc1, x1.x, w0); fma4(acc1, x1.y, w1); fma4(acc1, x1.z, w2); fma4(acc1, x1.w, w3);
      fma4(acc2, x2.x, w0); fma4(acc2, x2.y, w1); fma4(acc2, x2.z, w2); fma4(acc2, x2.w, w3);
      fma4(acc3, x3.x, w0); fma4(acc3, x3.y, w1); fma4(acc3, x3.z, w2); fma4(acc3, x3.w, w3);
    }
  }

  const float4 bias = *(const float4*)&bl[c0];
  float4 accs[4] = {acc0, acc1, acc2, acc3};
#pragma unroll
  for (int i = 0; i < 4; ++i) {
    const int grow = rbase + r0 + i;
    if (grow < N_NODES) {
      const float g = (deg[grow] > 0) ? 1.0f : 0.0f;
      float4 r;
      r.x = fmaxf(accs[i].x + bias.x * g, 0.0f);
      r.y = fmaxf(accs[i].y + bias.y * g, 0.0f);
      r.z = fmaxf(accs[i].z + bias.z * g, 0.0f);
      r.w = fmaxf(accs[i].w + bias.w * g, 0.0f);
      ((float4*)H)[(size_t)grow * 16 + tc] = r;
    }
  }
}

// ---------------------------------------------------------------------------
// GEMM1: h1 = h @ Wl1.T + bl1 (cols 0-31), hr1 = h @ Wr1.T (cols 32-63).
// Same micro-structure, K=64 single stage.
// ---------------------------------------------------------------------------
__global__ __launch_bounds__(256) void gemm1_kernel(
    const float* __restrict__ H, const float* __restrict__ Wl,
    const float* __restrict__ bl, const float* __restrict__ Wr,
    float* __restrict__ H1, float* __restrict__ HR1) {
  __shared__ float sW[64][68];
  __shared__ float sX[64][68];
  const int t = threadIdx.x;
  const int rbase = blockIdx.x * 64;

  for (int idx = t; idx < 32 * 64; idx += 256) {
    const int c = idx >> 6, k = idx & 63;  // c 0..31
    sW[k][c] = Wl[idx];
    sW[k][c + 32] = Wr[idx];
  }
  const float4* __restrict__ B4 = (const float4*)H;
  for (int f = t; f < 1024; f += 256) {
    const int row = f >> 4, kq = f & 15;
    const int grow = rbase + row;
    float4 v = {0, 0, 0, 0};
    if (grow < N_NODES) v = B4[(size_t)grow * 16 + kq];
    *(float4*)&sX[row][kq * 4] = v;
  }
  __syncthreads();

  const int tc = t & 15, tr = t >> 4;
  const int c0 = tc * 4, r0 = tr * 4;
  float4 acc0 = {0, 0, 0, 0}, acc1 = {0, 0, 0, 0};
  float4 acc2 = {0, 0, 0, 0}, acc3 = {0, 0, 0, 0};
#pragma unroll 4
  for (int kc = 0; kc < 64; kc += 4) {
    float4 x0 = *(const float4*)&sX[r0 + 0][kc];
    float4 x1 = *(const float4*)&sX[r0 + 1][kc];
    float4 x2 = *(const float4*)&sX[r0 + 2][kc];
    float4 x3 = *(const float4*)&sX[r0 + 3][kc];
    float4 w0 = *(const float4*)&sW[kc + 0][c0];
    float4 w1 = *(const float4*)&sW[kc + 1][c0];
    float4 w2 = *(const float4*)&sW[kc + 2][c0];
    float4 w3 = *(const float4*)&sW[kc + 3][c0];
    fma4(acc0, x0.x, w0); fma4(acc0, x0.y, w1); fma4(acc0, x0.z, w2); fma4(acc0, x0.w, w3);
    fma4(acc1, x1.x, w0); fma4(acc1, x1.y, w1); fma4(acc1, x1.z, w2); fma4(acc1, x1.w, w3);
    fma4(acc2, x2.x, w0); fma4(acc2, x2.y, w1); fma4(acc2, x2.z, w2); fma4(acc2, x2.w, w3);
    fma4(acc3, x3.x, w0); fma4(acc3, x3.y, w1); fma4(acc3, x3.z, w2); fma4(acc3, x3.w, w3);
  }

  const bool left = c0 < 32;
  float4 bias = {0, 0, 0, 0};
  if (left) bias = *(const float4*)&bl[c0];
  float4 accs[4] = {acc0, acc1, acc2, acc3};
#pragma unroll
  for (int i = 0; i < 4; ++i) {
    const int grow = rbase + r0 + i;
    if (grow < N_NODES) {
      float4 r;
      r.x = accs[i].x + bias.x;
      r.y = accs[i].y + bias.y;
      r.z = accs[i].z + bias.z;
      r.w = accs[i].w + bias.w;
      if (left)
        ((float4*)H1)[(size_t)grow * 8 + tc] = r;
      else
        ((float4*)HR1)[(size_t)grow * 8 + (tc - 8)] = r;
    }
  }
}

// ---------------------------------------------------------------------------
// CSR build, locality-ranged (blockIdx.y = dst sub-range pass).
// ---------------------------------------------------------------------------
__global__ __launch_bounds__(256) void count_ranged(const int* __restrict__ ei,
                                                    unsigned* __restrict__ deg) {
  const int lo = blockIdx.y * (N_NODES / 8), hi = lo + (N_NODES / 8);
  const int base = blockIdx.x * 2048;
#pragma unroll
  for (int i = 0; i < 8; ++i) {
    const int e = base + i * 256 + threadIdx.x;
    if (e < N_EDGES) {
      const int d = ei[N_EDGES + e];
      if (d >= lo && d < hi) atomicAdd(&deg[d], 1u);
    }
  }
}

__global__ __launch_bounds__(256) void scan_block(
    const unsigned* __restrict__ deg, unsigned* __restrict__ rowptr,
    unsigned* __restrict__ bsum) {
  __shared__ unsigned s[256];
  const int t = threadIdx.x;
  const int i = blockIdx.x * 256 + t;
  const unsigned v = (i < N_NODES) ? deg[i] : 0u;
  s[t] = v;
  __syncthreads();
  for (int off = 1; off < 256; off <<= 1) {
    const unsigned u = (t >= off) ? s[t - off] : 0u;
    __syncthreads();
    s[t] += u;
    __syncthreads();
  }
  if (i < N_NODES) rowptr[i] = s[t] - v;
  if (t == 255) bsum[blockIdx.x] = s[255];
}

__global__ __launch_bounds__(512) void scan_sums(
    const unsigned* __restrict__ bsum, unsigned* __restrict__ boff) {
  __shared__ unsigned s[512];
  const int t = threadIdx.x;
  const unsigned v = (t < NB_SCAN) ? bsum[t] : 0u;
  s[t] = v;
  __syncthreads();
  for (int off = 1; off < 512; off <<= 1) {
    const unsigned u = (t >= off) ? s[t - off] : 0u;
    __syncthreads();
    s[t] += u;
    __syncthreads();
  }
  if (t < NB_SCAN) boff[t] = s[t] - v;
}

__global__ __launch_bounds__(256) void scan_add(
    unsigned* __restrict__ rowptr, const unsigned* __restrict__ boff,
    unsigned* __restrict__ cursor) {
  const int i = blockIdx.x * 256 + threadIdx.x;
  if (i == 0) rowptr[N_NODES] = N_EDGES;
  if (i < N_NODES) {
    const unsigned r = rowptr[i] + boff[blockIdx.x];
    rowptr[i] = r;
    cursor[i] = r;
  }
}

__global__ __launch_bounds__(256) void fill_ranged(
    const int* __restrict__ ei, unsigned* __restrict__ cursor,
    unsigned* __restrict__ csr_src) {
  const int lo = blockIdx.y * (N_NODES / 8), hi = lo + (N_NODES / 8);
  const int base = blockIdx.x * 2048;
#pragma unroll
  for (int i = 0; i < 8; ++i) {
    const int e = base + i * 256 + threadIdx.x;
    if (e < N_EDGES) {
      const int d = ei[N_EDGES + e];
      if (d >= lo && d < hi) {
        const unsigned pos = atomicAdd(&cursor[d], 1u);
        csr_src[pos] = (unsigned)ei[e];
      }
    }
  }
}

// ---------------------------------------------------------------------------
// Gather-aggregate (mean) + optional base add: one wave per dst node.
// ---------------------------------------------------------------------------
template <int F, bool HAS_BASE>
__global__ __launch_bounds__(256) void gather_comb(
    const float* __restrict__ H, const unsigned* __restrict__ rowptr,
    const unsigned* __restrict__ csr_src, const float* __restrict__ base_row,
    float* __restrict__ outp) {
  constexpr int G = F / 4;
  constexpr int NG = 64 / G;
  const int node = (int)((blockIdx.x * 256 + threadIdx.x) >> 6);
  const int lane = threadIdx.x & 63;
  if (node >= N_NODES) return;
  const int g = lane / G, q = lane % G;
  const unsigned beg = rowptr[node], end = rowptr[node + 1];
  const float inv = (end > beg) ? 1.0f / (float)(end - beg) : 0.0f;
  const float4* __restrict__ H4 = (const float4*)H;

  float4 a0 = {0.f, 0.f, 0.f, 0.f}, a1 = {0.f, 0.f, 0.f, 0.f};
  unsigned e = beg + g;
  for (; e + NG < end; e += 2 * NG) {
    const unsigned s0 = csr_src[e], s1 = csr_src[e + NG];
    const float4 v0 = H4[(size_t)s0 * G + q];
    const float4 v1 = H4[(size_t)s1 * G + q];
    a0.x += v0.x; a0.y += v0.y; a0.z += v0.z; a0.w += v0.w;
    a1.x += v1.x; a1.y += v1.y; a1.z += v1.z; a1.w += v1.w;
  }
  if (e < end) {
    const float4 v = H4[(size_t)csr_src[e] * G + q];
    a0.x += v.x; a0.y += v.y; a0.z += v.z; a0.w += v.w;
  }
  float sx = a0.x + a1.x, sy = a0.y + a1.y;
  float sz = a0.z + a1.z, sw = a0.w + a1.w;
#pragma unroll
  for (int m = G; m < 64; m <<= 1) {
    sx += __shfl_xor(sx, m, 64);
    sy += __shfl_xor(sy, m, 64);
    sz += __shfl_xor(sz, m, 64);
    sw += __shfl_xor(sw, m, 64);
  }
  if (g == 0) {
    float4 r;
    r.x = sx * inv; r.y = sy * inv; r.z = sz * inv; r.w = sw * inv;
    if (HAS_BASE) {
      const float4 b = ((const float4*)base_row)[(size_t)node * G + q];
      r.x += b.x; r.y += b.y; r.z += b.z; r.w += b.w;
    }
    ((float4*)outp)[(size_t)node * G + q] = r;
  }
}

extern "C" void kernel_launch(void* const* d_in, const int* in_sizes, int n_in,
                              void* d_out, int out_size, void* d_ws,
                              size_t ws_size, hipStream_t stream) {
  const float* x = (const float*)d_in[0];
  const int* ei = (const int*)d_in[1];
  const float* Wl0 = (const float*)d_in[2];
  const float* bl0 = (const float*)d_in[3];
  const float* Wr0 = (const float*)d_in[4];
  const float* Wl1 = (const float*)d_in[5];
  const float* bl1 = (const float*)d_in[6];
  const float* Wr1 = (const float*)d_in[7];
  float* out = (float*)d_out;

  const int N = N_NODES;

  // Workspace:
  //   bufA : N*64 f32  aggx = mean(x[src]); later h1 [N,32] + hr1 [N,32]
  //   bufB : N*64 f32  h (layer-0 output)
  //   deg, rowptr[N+1], cursor, bsum[512], boff[512], csr_src[E] : u32
  float* bufA = (float*)d_ws;
  float* bufB = bufA + (size_t)N * 64;
  unsigned* deg = (unsigned*)(bufB + (size_t)N * 64);
  unsigned* rowptr = deg + N;
  unsigned* cursor = rowptr + (N + 1);
  unsigned* bsum = cursor + N;
  unsigned* boff = bsum + 512;
  unsigned* csr_src = boff + 512;
  float* h1 = bufA;
  float* hr1 = bufA + (size_t)N * 32;

  hipMemsetAsync(deg, 0, (size_t)N * sizeof(unsigned), stream);

  const dim3 blk(256);

  // ---- CSR build (graph identical for both layers) ----
  count_ranged<<<dim3(EBLK, 8), blk, 0, stream>>>(ei, deg);
  scan_block<<<NB_SCAN, blk, 0, stream>>>(deg, rowptr, bsum);
  scan_sums<<<1, 512, 0, stream>>>(bsum, boff);
  scan_add<<<NB_SCAN, blk, 0, stream>>>(rowptr, boff, cursor);
  fill_ranged<<<dim3(EBLK, 8), blk, 0, stream>>>(ei, cursor, csr_src);

  // ---- Layer 0 (linearity: aggregate raw x, then one fused GEMM) ----
  // aggx = mean(x[src])
  gather_comb<64, false><<<(N * 64 + 255) / 256, blk, 0, stream>>>(
      x, rowptr, csr_src, nullptr, bufA);
  // h = relu(Wr0@x + Wl0@aggx + bl0*(deg>0))
  gemm0_kernel<<<NTILES, blk, 0, stream>>>(x, bufA, Wr0, Wl0, bl0, deg, bufB);

  // ---- Layer 1 ----
  // h1 = h@Wl1.T + bl1 ; hr1 = h@Wr1.T
  gemm1_kernel<<<NTILES, blk, 0, stream>>>(bufB, Wl1, bl1, Wr1, h1, hr1);
  // out = mean(h1[src]) + hr1
  gather_comb<32, true><<<(N * 64 + 255) / 256, blk, 0, stream>>>(
      h1, rowptr, csr_src, hr1, out);
}

// Round 5
// 306.422 us; speedup vs baseline: 2.5255x; 1.0470x over previous
//
#include <hip/hip_runtime.h>

#define N_NODES 100000
#define N_EDGES 1600000
#define NB_SCAN ((N_NODES + 255) / 256)  // 391 blocks of 256
#define EBLK ((N_EDGES + 2047) / 2048)   // 782 blocks of 2048 edges
#define NTILES ((N_NODES + 63) / 64)     // 1563 row tiles of 64

__device__ __forceinline__ void fma4(float4& a, float s, const float4& w) {
  a.x = fmaf(s, w.x, a.x);
  a.y = fmaf(s, w.y, a.y);
  a.z = fmaf(s, w.z, a.z);
  a.w = fmaf(s, w.w, a.w);
}

// ---------------------------------------------------------------------------
// Fused GEMM0+GEMM1:
//   phase 1: h = relu(Wr0@x + Wl0@aggx + bl0*(deg>0))      (64-row tile)
//   phase 2: h1 = h@Wl1.T + bl1 ; hr1 = h@Wr1.T            (h stays in LDS)
// 256 thr = 16 col-groups x 16 row-groups, 4x4 micro-tile, LDS padded to 68.
// h never touches global memory.
// ---------------------------------------------------------------------------
__global__ __launch_bounds__(256) void gemm01_kernel(
    const float* __restrict__ X, const float* __restrict__ AGG,
    const float* __restrict__ Wr0, const float* __restrict__ Wl0,
    const float* __restrict__ bl0, const unsigned* __restrict__ deg,
    const float* __restrict__ Wl1, const float* __restrict__ bl1,
    const float* __restrict__ Wr1, float* __restrict__ H1,
    float* __restrict__ HR1) {
  __shared__ float sW[128][68];
  __shared__ float sX[64][68];
  const int t = threadIdx.x;
  const int rbase = blockIdx.x * 64;

  // stage layer-0 weights: sW[k][c] = Wr0[c][k] (k<64), Wl0[c][k-64]
  for (int idx = t; idx < 64 * 64; idx += 256) {
    const int c = idx >> 6, k = idx & 63;
    sW[k][c] = Wr0[idx];
    sW[k + 64][c] = Wl0[idx];
  }

  const int tc = t & 15, tr = t >> 4;
  const int c0 = tc * 4, r0 = tr * 4;
  float4 acc0 = {0, 0, 0, 0}, acc1 = {0, 0, 0, 0};
  float4 acc2 = {0, 0, 0, 0}, acc3 = {0, 0, 0, 0};

  const float* bufs[2] = {X, AGG};
  for (int half = 0; half < 2; ++half) {
    if (half) __syncthreads();
    const float4* __restrict__ B4 = (const float4*)bufs[half];
    for (int f = t; f < 1024; f += 256) {  // 64 rows x 16 float4
      const int row = f >> 4, kq = f & 15;
      const int grow = rbase + row;
      float4 v = {0, 0, 0, 0};
      if (grow < N_NODES) v = B4[(size_t)grow * 16 + kq];
      *(float4*)&sX[row][kq * 4] = v;
    }
    __syncthreads();
    const int kb = half * 64;
#pragma unroll 4
    for (int kc = 0; kc < 64; kc += 4) {
      float4 x0 = *(const float4*)&sX[r0 + 0][kc];
      float4 x1 = *(const float4*)&sX[r0 + 1][kc];
      float4 x2 = *(const float4*)&sX[r0 + 2][kc];
      float4 x3 = *(const float4*)&sX[r0 + 3][kc];
      float4 w0 = *(const float4*)&sW[kb + kc + 0][c0];
      float4 w1 = *(const float4*)&sW[kb + kc + 1][c0];
      float4 w2 = *(const float4*)&sW[kb + kc + 2][c0];
      float4 w3 = *(const float4*)&sW[kb + kc + 3][c0];
      fma4(acc0, x0.x, w0); fma4(acc0, x0.y, w1); fma4(acc0, x0.z, w2); fma4(acc0, x0.w, w3);
      fma4(acc1, x1.x, w0); fma4(acc1, x1.y, w1); fma4(acc1, x1.z, w2); fma4(acc1, x1.w, w3);
      fma4(acc2, x2.x, w0); fma4(acc2, x2.y, w1); fma4(acc2, x2.z, w2); fma4(acc2, x2.w, w3);
      fma4(acc3, x3.x, w0); fma4(acc3, x3.y, w1); fma4(acc3, x3.z, w2); fma4(acc3, x3.w, w3);
    }
  }

  // epilogue 0 -> h tile into sX (never to global)
  __syncthreads();  // everyone done reading sX (AGG half)
  {
    const float4 bias = *(const float4*)&bl0[c0];
    float4 accs[4] = {acc0, acc1, acc2, acc3};
#pragma unroll
    for (int i = 0; i < 4; ++i) {
      const int grow = rbase + r0 + i;
      const float g = (grow < N_NODES && deg[grow] > 0) ? 1.0f : 0.0f;
      float4 r;
      r.x = fmaxf(accs[i].x + bias.x * g, 0.0f);
      r.y = fmaxf(accs[i].y + bias.y * g, 0.0f);
      r.z = fmaxf(accs[i].z + bias.z * g, 0.0f);
      r.w = fmaxf(accs[i].w + bias.w * g, 0.0f);
      *(float4*)&sX[r0 + i][c0] = r;
    }
  }
  // stage layer-1 weights: sW[k][c] = Wl1[c][k] (c<32), Wr1[c-32][k]
  for (int idx = t; idx < 32 * 64; idx += 256) {
    const int c = idx >> 6, k = idx & 63;  // c 0..31
    sW[k][c] = Wl1[idx];
    sW[k][c + 32] = Wr1[idx];
  }
  __syncthreads();

  acc0 = {0, 0, 0, 0}; acc1 = {0, 0, 0, 0};
  acc2 = {0, 0, 0, 0}; acc3 = {0, 0, 0, 0};
#pragma unroll 4
  for (int kc = 0; kc < 64; kc += 4) {
    float4 x0 = *(const float4*)&sX[r0 + 0][kc];
    float4 x1 = *(const float4*)&sX[r0 + 1][kc];
    float4 x2 = *(const float4*)&sX[r0 + 2][kc];
    float4 x3 = *(const float4*)&sX[r0 + 3][kc];
    float4 w0 = *(const float4*)&sW[kc + 0][c0];
    float4 w1 = *(const float4*)&sW[kc + 1][c0];
    float4 w2 = *(const float4*)&sW[kc + 2][c0];
    float4 w3 = *(const float4*)&sW[kc + 3][c0];
    fma4(acc0, x0.x, w0); fma4(acc0, x0.y, w1); fma4(acc0, x0.z, w2); fma4(acc0, x0.w, w3);
    fma4(acc1, x1.x, w0); fma4(acc1, x1.y, w1); fma4(acc1, x1.z, w2); fma4(acc1, x1.w, w3);
    fma4(acc2, x2.x, w0); fma4(acc2, x2.y, w1); fma4(acc2, x2.z, w2); fma4(acc2, x2.w, w3);
    fma4(acc3, x3.x, w0); fma4(acc3, x3.y, w1); fma4(acc3, x3.z, w2); fma4(acc3, x3.w, w3);
  }

  const bool left = c0 < 32;
  float4 bias = {0, 0, 0, 0};
  if (left) bias = *(const float4*)&bl1[c0];
  float4 accs[4] = {acc0, acc1, acc2, acc3};
#pragma unroll
  for (int i = 0; i < 4; ++i) {
    const int grow = rbase + r0 + i;
    if (grow < N_NODES) {
      float4 r;
      r.x = accs[i].x + bias.x;
      r.y = accs[i].y + bias.y;
      r.z = accs[i].z + bias.z;
      r.w = accs[i].w + bias.w;
      if (left)
        ((float4*)H1)[(size_t)grow * 8 + tc] = r;
      else
        ((float4*)HR1)[(size_t)grow * 8 + (tc - 8)] = r;
    }
  }
}

// ---------------------------------------------------------------------------
// CSR build. count: single pass (atomics are memory-side RMW, no write
// amplification). fill: window = blockIdx.x & 7 -> all writers of one csr
// window land on ONE XCD (round-robin dispatch), so its L2 merges the
// scattered 4B stores into full lines before eviction.
// ---------------------------------------------------------------------------
__global__ __launch_bounds__(256) void count_plain(const int* __restrict__ ei,
                                                   unsigned* __restrict__ deg) {
  const int base = blockIdx.x * 2048;
#pragma unroll
  for (int i = 0; i < 8; ++i) {
    const int e = base + i * 256 + threadIdx.x;
    if (e < N_EDGES) atomicAdd(&deg[ei[N_EDGES + e]], 1u);
  }
}

__global__ __launch_bounds__(256) void scan_block(
    const unsigned* __restrict__ deg, unsigned* __restrict__ rowptr,
    unsigned* __restrict__ bsum) {
  __shared__ unsigned s[256];
  const int t = threadIdx.x;
  const int i = blockIdx.x * 256 + t;
  const unsigned v = (i < N_NODES) ? deg[i] : 0u;
  s[t] = v;
  __syncthreads();
  for (int off = 1; off < 256; off <<= 1) {
    const unsigned u = (t >= off) ? s[t - off] : 0u;
    __syncthreads();
    s[t] += u;
    __syncthreads();
  }
  if (i < N_NODES) rowptr[i] = s[t] - v;
  if (t == 255) bsum[blockIdx.x] = s[255];
}

__global__ __launch_bounds__(512) void scan_sums(
    const unsigned* __restrict__ bsum, unsigned* __restrict__ boff) {
  __shared__ unsigned s[512];
  const int t = threadIdx.x;
  const unsigned v = (t < NB_SCAN) ? bsum[t] : 0u;
  s[t] = v;
  __syncthreads();
  for (int off = 1; off < 512; off <<= 1) {
    const unsigned u = (t >= off) ? s[t - off] : 0u;
    __syncthreads();
    s[t] += u;
    __syncthreads();
  }
  if (t < NB_SCAN) boff[t] = s[t] - v;
}

__global__ __launch_bounds__(256) void scan_add(
    unsigned* __restrict__ rowptr, const unsigned* __restrict__ boff,
    unsigned* __restrict__ cursor) {
  const int i = blockIdx.x * 256 + threadIdx.x;
  if (i == 0) rowptr[N_NODES] = N_EDGES;
  if (i < N_NODES) {
    const unsigned r = rowptr[i] + boff[blockIdx.x];
    rowptr[i] = r;
    cursor[i] = r;
  }
}

__global__ __launch_bounds__(256) void fill_xcd(
    const int* __restrict__ ei, unsigned* __restrict__ cursor,
    unsigned* __restrict__ csr_src) {
  const int win = blockIdx.x & 7;          // -> XCD (round-robin dispatch)
  const int chunk = blockIdx.x >> 3;
  const int lo = win * (N_NODES / 8), hi = lo + (N_NODES / 8);
  const int base = chunk * 2048;
#pragma unroll
  for (int i = 0; i < 8; ++i) {
    const int e = base + i * 256 + threadIdx.x;
    if (e < N_EDGES) {
      const int d = ei[N_EDGES + e];
      if (d >= lo && d < hi) {
        const unsigned pos = atomicAdd(&cursor[d], 1u);
        csr_src[pos] = (unsigned)ei[e];
      }
    }
  }
}

// ---------------------------------------------------------------------------
// Gather-aggregate (mean) + optional base add: one wave per dst node.
// ---------------------------------------------------------------------------
template <int F, bool HAS_BASE>
__global__ __launch_bounds__(256) void gather_comb(
    const float* __restrict__ H, const unsigned* __restrict__ rowptr,
    const unsigned* __restrict__ csr_src, const float* __restrict__ base_row,
    float* __restrict__ outp) {
  constexpr int G = F / 4;
  constexpr int NG = 64 / G;
  const int node = (int)((blockIdx.x * 256 + threadIdx.x) >> 6);
  const int lane = threadIdx.x & 63;
  if (node >= N_NODES) return;
  const int g = lane / G, q = lane % G;
  const unsigned beg = rowptr[node], end = rowptr[node + 1];
  const float inv = (end > beg) ? 1.0f / (float)(end - beg) : 0.0f;
  const float4* __restrict__ H4 = (const float4*)H;

  float4 a0 = {0.f, 0.f, 0.f, 0.f}, a1 = {0.f, 0.f, 0.f, 0.f};
  unsigned e = beg + g;
  for (; e + NG < end; e += 2 * NG) {
    const unsigned s0 = csr_src[e], s1 = csr_src[e + NG];
    const float4 v0 = H4[(size_t)s0 * G + q];
    const float4 v1 = H4[(size_t)s1 * G + q];
    a0.x += v0.x; a0.y += v0.y; a0.z += v0.z; a0.w += v0.w;
    a1.x += v1.x; a1.y += v1.y; a1.z += v1.z; a1.w += v1.w;
  }
  if (e < end) {
    const float4 v = H4[(size_t)csr_src[e] * G + q];
    a0.x += v.x; a0.y += v.y; a0.z += v.z; a0.w += v.w;
  }
  float sx = a0.x + a1.x, sy = a0.y + a1.y;
  float sz = a0.z + a1.z, sw = a0.w + a1.w;
#pragma unroll
  for (int m = G; m < 64; m <<= 1) {
    sx += __shfl_xor(sx, m, 64);
    sy += __shfl_xor(sy, m, 64);
    sz += __shfl_xor(sz, m, 64);
    sw += __shfl_xor(sw, m, 64);
  }
  if (g == 0) {
    float4 r;
    r.x = sx * inv; r.y = sy * inv; r.z = sz * inv; r.w = sw * inv;
    if (HAS_BASE) {
      const float4 b = ((const float4*)base_row)[(size_t)node * G + q];
      r.x += b.x; r.y += b.y; r.z += b.z; r.w += b.w;
    }
    ((float4*)outp)[(size_t)node * G + q] = r;
  }
}

extern "C" void kernel_launch(void* const* d_in, const int* in_sizes, int n_in,
                              void* d_out, int out_size, void* d_ws,
                              size_t ws_size, hipStream_t stream) {
  const float* x = (const float*)d_in[0];
  const int* ei = (const int*)d_in[1];
  const float* Wl0 = (const float*)d_in[2];
  const float* bl0 = (const float*)d_in[3];
  const float* Wr0 = (const float*)d_in[4];
  const float* Wl1 = (const float*)d_in[5];
  const float* bl1 = (const float*)d_in[6];
  const float* Wr1 = (const float*)d_in[7];
  float* out = (float*)d_out;

  const int N = N_NODES;

  // Workspace:
  //   bufA : N*64 f32  aggx = mean(x[src]); h1 [N,32] + hr1 [N,32] after GEMM
  //   deg, rowptr[N+1], cursor, bsum[512], boff[512], csr_src[E] : u32
  float* bufA = (float*)d_ws;
  float* bufB = bufA + (size_t)N * 64;  // h1 / hr1 live here
  unsigned* deg = (unsigned*)(bufB + (size_t)N * 64);
  unsigned* rowptr = deg + N;
  unsigned* cursor = rowptr + (N + 1);
  unsigned* bsum = cursor + N;
  unsigned* boff = bsum + 512;
  unsigned* csr_src = boff + 512;
  float* h1 = bufB;
  float* hr1 = bufB + (size_t)N * 32;

  hipMemsetAsync(deg, 0, (size_t)N * sizeof(unsigned), stream);

  const dim3 blk(256);

  // ---- CSR build (graph identical for both layers) ----
  count_plain<<<EBLK, blk, 0, stream>>>(ei, deg);
  scan_block<<<NB_SCAN, blk, 0, stream>>>(deg, rowptr, bsum);
  scan_sums<<<1, 512, 0, stream>>>(bsum, boff);
  scan_add<<<NB_SCAN, blk, 0, stream>>>(rowptr, boff, cursor);
  fill_xcd<<<EBLK * 8, blk, 0, stream>>>(ei, cursor, csr_src);

  // ---- aggx = mean(x[src]) ----
  gather_comb<64, false><<<(N * 64 + 255) / 256, blk, 0, stream>>>(
      x, rowptr, csr_src, nullptr, bufA);

  // ---- fused GEMM0+GEMM1: h in LDS only; emits h1, hr1 ----
  gemm01_kernel<<<NTILES, blk, 0, stream>>>(x, bufA, Wr0, Wl0, bl0, deg, Wl1,
                                            bl1, Wr1, h1, hr1);

  // ---- out = mean(h1[src]) + hr1 ----
  gather_comb<32, true><<<(N * 64 + 255) / 256, blk, 0, stream>>>(
      h1, rowptr, csr_src, hr1, out);
}